// Round 16
// baseline (308.496 us; speedup 1.0000x reference)
//
#include <hip/hip_runtime.h>
#include <hip/hip_bf16.h>
#include <stdint.h>

// HealthAttention: out = (softmax(rope(XWq^T) rope(XWk^T)^T / sqrt(128)) XWv^T) Wo^T
// B=2 S=2048 D=2048 H=16 DH=128.  medical_bias -> softmax-invariant, dropped.
// R16: QKV/out-proj/f2bf reverted to R14 (925 TF local optimum; R12/R13/R15
// restructures all lost). k_attn: V-fragments hoisted to registers once per
// tile (vb[2][8], +64 VGPR) -> ds_read_b128 52->36 per tile per wave; attn
// was LDS-pipe-bound (52x12x8 waves ~ 83% of measured interval). Keeps R11's
// per-qq softmax||PV overlap.

#define B_ 2
#define S_ 2048
#define D_ 2048
#define H_ 16

typedef float f32x4 __attribute__((ext_vector_type(4)));
typedef short s16x8 __attribute__((ext_vector_type(8)));

__device__ __forceinline__ unsigned short f2bf(float f) {
  union { float f; uint32_t u; } c; c.f = f;
  return (unsigned short)((c.u + 0x7fffu + ((c.u >> 16) & 1u)) >> 16);
}

__device__ __forceinline__ unsigned short bfc(float f) {
  __hip_bfloat16 h = __float2bfloat16(f);
  unsigned short u;
  __builtin_memcpy(&u, &h, 2);
  return u;
}

#define FAST_EXP2(x) __builtin_amdgcn_exp2f(x)

__device__ __forceinline__ void gld_lds16(const void* g, void* l) {
  __builtin_amdgcn_global_load_lds(
      (const __attribute__((address_space(1))) uint32_t*)g,
      (__attribute__((address_space(3))) uint32_t*)l, 16, 0, 0);
}

// ------- fp32 -> bf16 convert (all 5 tensors) + rope table, one kernel -----
__global__ __launch_bounds__(256) void k_f2bf_all(
    const float* __restrict__ hs, const float* __restrict__ wq,
    const float* __restrict__ wk, const float* __restrict__ wv,
    const float* __restrict__ wo, unsigned short* __restrict__ hb,
    unsigned short* __restrict__ wall, float2* __restrict__ t2) {
  const int NH = 2097152, NW = 1048576;  // float4 units
  const int NF = NH + 4 * NW;            // convert work
  const int NT = 131072;                 // rope-table work (S*64)
  int i = blockIdx.x * 256 + threadIdx.x;
  const int stride = gridDim.x * 256;
  for (; i < NF + NT; i += stride) {
    if (i < NF) {
      f32x4 v;
      ushort4* dst;
      if (i < NH) {
        v = ((const f32x4*)hs)[i];
        dst = (ushort4*)hb + i;
      } else {
        const int j = i - NH;
        const int rgn = j >> 20;
        const int o = j & (NW - 1);
        const float* s = (rgn == 0) ? wq : (rgn == 1) ? wk : (rgn == 2) ? wv : wo;
        v = ((const f32x4*)s)[o];
        dst = (ushort4*)wall + j;
      }
      ushort4 u;
      u.x = f2bf(v.x); u.y = f2bf(v.y); u.z = f2bf(v.z); u.w = f2bf(v.w);
      *dst = u;
    } else {
      const int t = i - NF;              // 0..131071
      const int s = t >> 6, j = t & 63;
      float inv = expf(-(float)j * (1.0f / 64.0f) * 9.210340371976184f);
      float sv, cv;
      sincosf((float)s * inv, &sv, &cv);
      t2[t] = float2{cv, sv};
    }
  }
}

// ---------------- GEMM: C[M,N] = A[M,K] @ W[N,K]^T  (bf16 in, fp32 acc) -----
// 128x128 tile, BK=64, 4 row-stacked waves (each: 32 rows x 128 cols),
// 16x16x32 MFMA, XCD-swizzled grid, double-buffered swizzled LDS,
// early-STAGE pipeline (1 barrier per K-step).
// plain=1: fp32 to C0.  plain=0: z=0 -> RoPE+scale -> bf16 Qo;
// z=1 -> RoPE -> bf16 Ko; z=2 -> bf16 transposed per-head to VT.
__global__ __launch_bounds__(256, 2) void k_gemm(
    const unsigned short* __restrict__ A,
    const unsigned short* __restrict__ W0,
    const unsigned short* __restrict__ W1,
    const unsigned short* __restrict__ W2,
    float* __restrict__ C0,
    unsigned short* __restrict__ Qo,
    unsigned short* __restrict__ Ko,
    unsigned short* __restrict__ VT,
    const float2* __restrict__ tab,
    int plain) {
  __shared__ unsigned short Al[2][128 * 64];
  __shared__ unsigned short Bl[2][128 * 64];

  // bijective XCD remap: hw linear id (x fastest, z slowest), nwg % 8 == 0
  const int l0 = ((int)blockIdx.z * 32 + (int)blockIdx.y) * 16 + (int)blockIdx.x;
  const int qx = ((int)gridDim.z * 512) >> 3;  // blocks per XCD
  const int wg = (l0 & 7) * qx + (l0 >> 3);
  const int z = wg >> 9;
  const unsigned short* __restrict__ Wp = (z == 0) ? W0 : (z == 1) ? W1 : W2;

  const int tid = threadIdx.x;
  const int w = tid >> 6;
  const int l = tid & 63;
  const int row0 = ((wg >> 4) & 31) * 128;
  const int col0 = (wg & 15) * 128;

  const int c16 = l & 15, g = l >> 4;
  const int cx = c16 & 7;

  // staging: lane covers row jj*8 + (l>>3), 16B slot (l&7); source slot
  // pre-swizzled so LDS[row][slot] = global[row][slot ^ (row&7)].
  const int srow = l >> 3;
  const int scol = ((l & 7) ^ (l >> 3)) << 3;  // source col in bf16 elems

  // ds_read lane bases (bytes): addr = base + kbase[kk] (+ m*2048 / n*2048)
  int kbase[2];
#pragma unroll
  for (int kk = 0; kk < 2; ++kk)
    kbase[kk] = c16 * 128 + (((kk * 4 + g) ^ cx) << 4);
  const char* AW0 = (const char*)&Al[0][0] + w * 4096;
  const char* AW1 = (const char*)&Al[1][0] + w * 4096;
  const char* BB0 = (const char*)&Bl[0][0];
  const char* BB1 = (const char*)&Bl[1][0];

  f32x4 acc[2][8];
#pragma unroll
  for (int m = 0; m < 2; ++m)
#pragma unroll
    for (int n = 0; n < 8; ++n)
      acc[m][n] = f32x4{0.f, 0.f, 0.f, 0.f};

#define STAGE_G(K0, BUF)                                                       \
  do {                                                                         \
    _Pragma("unroll") for (int i = 0; i < 4; ++i) {                            \
      const int jj = (w << 2) + i;                                             \
      gld_lds16(&A[(size_t)(row0 + (jj << 3) + srow) * 2048 + (K0) + scol],    \
                &Al[BUF][jj * 512]);                                           \
      gld_lds16(&Wp[(size_t)(col0 + (jj << 3) + srow) * 2048 + (K0) + scol],   \
                &Bl[BUF][jj * 512]);                                           \
    }                                                                          \
  } while (0)

#define COMPUTE_G(AW, BBp)                                                     \
  do {                                                                         \
    _Pragma("unroll") for (int kk = 0; kk < 2; ++kk) {                         \
      s16x8 a[2], b[8];                                                        \
      _Pragma("unroll") for (int m = 0; m < 2; ++m)                            \
          a[m] = *(const s16x8*)((AW) + m * 2048 + kbase[kk]);                 \
      _Pragma("unroll") for (int n = 0; n < 8; ++n)                            \
          b[n] = *(const s16x8*)((BBp) + n * 2048 + kbase[kk]);                \
      __builtin_amdgcn_s_setprio(1);                                           \
      _Pragma("unroll") for (int m = 0; m < 2; ++m)                            \
          _Pragma("unroll") for (int n = 0; n < 8; ++n)                        \
              acc[m][n] = __builtin_amdgcn_mfma_f32_16x16x32_bf16(             \
                  a[m], b[n], acc[m][n], 0, 0, 0);                             \
      __builtin_amdgcn_s_setprio(0);                                           \
    }                                                                          \
  } while (0)

  STAGE_G(0, 0);
  __syncthreads();
  for (int k0 = 0; k0 < 2048; k0 += 128) {
    STAGE_G(k0 + 64, 1);  // prefetch next K-tile while computing current
    COMPUTE_G(AW0, BB0);
    __syncthreads();      // vmcnt drain amortized under the 32 MFMAs above
    if (k0 + 128 < 2048) STAGE_G(k0 + 128, 0);
    COMPUTE_G(AW1, BB1);
    __syncthreads();
  }
#undef STAGE_G
#undef COMPUTE_G

  if (plain) {
#pragma unroll
    for (int m = 0; m < 2; ++m) {
      const int gr = row0 + w * 32 + m * 16 + g * 4;
#pragma unroll
      for (int n = 0; n < 8; ++n) {
        const int gc = col0 + n * 16 + c16;
#pragma unroll
        for (int r = 0; r < 4; ++r)
          C0[(size_t)(gr + r) * 2048 + gc] = acc[m][n][r];
      }
    }
  } else if (z == 2) {
    // V: write bf16 transposed per-head: VT[((b*16+h)*128+dh)*2048 + s]
#pragma unroll
    for (int m = 0; m < 2; ++m) {
      const int gr = row0 + w * 32 + m * 16 + g * 4;  // 4 consecutive s
      const int b_ = gr >> 11, s_ = gr & 2047;
#pragma unroll
      for (int n = 0; n < 8; ++n) {
        const int gc = col0 + n * 16 + c16;  // h*128+dh
        ushort4 o;
        o.x = f2bf(acc[m][n][0]);
        o.y = f2bf(acc[m][n][1]);
        o.z = f2bf(acc[m][n][2]);
        o.w = f2bf(acc[m][n][3]);
        *(ushort4*)&VT[((size_t)(b_ * 2048 + gc)) * 2048 + s_] = o;
      }
    }
  } else {
    // Q/K: in-register RoPE.  cols col0 + j and col0 + 64 + j are lane-local
    // (acc[m][n], acc[m][n+4]).  Q additionally scaled by (1/sqrt(128))*log2e
    // so attention can use exp2.
    unsigned short* __restrict__ O = z ? Ko : Qo;
    const float sc = z ? 1.0f : (0.08838834764831845f * 1.4426950408889634f);
#pragma unroll
    for (int m = 0; m < 2; ++m) {
#pragma unroll
      for (int r = 0; r < 4; ++r) {
        const int gr = row0 + w * 32 + m * 16 + g * 4 + r;
        const int s_ = gr & 2047;
#pragma unroll
        for (int n = 0; n < 4; ++n) {
          const float2 f = tab[s_ * 64 + n * 16 + c16];
          const float x1 = acc[m][n][r], x2 = acc[m][n + 4][r];
          O[(size_t)gr * 2048 + col0 + n * 16 + c16] =
              f2bf((x1 * f.x - x2 * f.y) * sc);
          O[(size_t)gr * 2048 + col0 + 64 + n * 16 + c16] =
              f2bf((x2 * f.x + x1 * f.y) * sc);
        }
      }
    }
  }
}

// ---------------- flash attention (pipelined, swizzled LDS) ----------------
// grid (16, 32): 512 blocks, XCD-remapped so each (b,h) lives on one XCD.
// 4 waves x 32 q-rows; K/V double-buffered; 1 barrier per 64-key tile.
// V-fragments hoisted to registers once per tile (vb[2][8]); per-qq P buffer
// reused; softmax(qq1) overlaps PV(qq0). Scores pre-scaled by
// (1/sqrt(128))*log2e -> exp2 softmax.
__global__ __launch_bounds__(256, 2) void k_attn(
    const unsigned short* __restrict__ Qb,
    const unsigned short* __restrict__ Kb,
    const unsigned short* __restrict__ Vt,
    unsigned short* __restrict__ Ob) {
  __shared__ unsigned short Kl[2][64 * 128];   // [key][d]  swizzled, 2x16KB
  __shared__ unsigned short Vl[2][128 * 64];   // [d][key]  swizzled, 2x16KB
  __shared__ unsigned short Pl[4][16 * 64];    // per-wave per-qq P, 8KB

  const int l0 = (int)blockIdx.y * 16 + (int)blockIdx.x;
  const int wg = (l0 & 7) * 64 + (l0 >> 3);
  const int bh = wg >> 4;
  const int b = bh >> 4, h = bh & 15;

  const int tid = threadIdx.x, w = tid >> 6, l = tid & 63;
  const int q0 = (wg & 15) * 128 + w * 32;
  const int g = l >> 4, c16 = l & 15;
  const int cx = c16 & 7;  // row&7 for rows of form n*16+c16

  // hoisted swizzled LDS read offsets (bytes, lane-only)
  int kaddr[4], vaddr[2];
#pragma unroll
  for (int kc = 0; kc < 4; ++kc)
    kaddr[kc] = c16 * 256 + ((((kc * 4 + g) ^ cx)) << 4);
#pragma unroll
  for (int kc2 = 0; kc2 < 2; ++kc2)
    vaddr[kc2] = c16 * 128 + ((((kc2 * 4 + g) ^ cx)) << 4);
  const char* PW = (const char*)&Pl[w][0];

  // Q fragments in registers (pre-scaled by (1/sqrt(128))*log2e)
  s16x8 qf[2][4];
#pragma unroll
  for (int qq = 0; qq < 2; ++qq)
#pragma unroll
    for (int kc = 0; kc < 4; ++kc)
      qf[qq][kc] = *(const s16x8*)&Qb[(size_t)(b * 2048 + q0 + qq * 16 + c16) * 2048 +
                                      h * 128 + kc * 32 + g * 8];

  f32x4 oacc[2][8];
  float mrow[2][4], lrow[2][4];  // lrow: per-lane partial sums
#pragma unroll
  for (int qq = 0; qq < 2; ++qq) {
#pragma unroll
    for (int df = 0; df < 8; ++df) oacc[qq][df] = f32x4{0.f, 0.f, 0.f, 0.f};
#pragma unroll
    for (int r = 0; r < 4; ++r) { mrow[qq][r] = -INFINITY; lrow[qq][r] = 0.f; }
  }

#define STAGE(T, BUF)                                                          \
  do {                                                                         \
    _Pragma("unroll") for (int i = 0; i < 4; ++i) {                            \
      const int jj = (w << 2) + i;                                             \
      const int krow = jj * 4 + (l >> 4);                                      \
      const int kslot = (l & 15) ^ (krow & 7);                                 \
      gld_lds16(&Kb[(size_t)(b * 2048 + (T) + krow) * 2048 + h * 128 +        \
                    (kslot << 3)],                                             \
                &Kl[BUF][jj * 512]);                                           \
      const int vrow = jj * 8 + (l >> 3);                                      \
      const int vslot = (l & 7) ^ (vrow & 7);                                  \
      gld_lds16(&Vt[(size_t)(bh * 128 + vrow) * 2048 + (T) + (vslot << 3)],    \
                &Vl[BUF][jj * 512]);                                           \
    }                                                                          \
  } while (0)

#define COMPUTE(BUF_)                                                          \
  do {                                                                         \
    f32x4 sacc[2][4];                                                          \
    _Pragma("unroll") for (int qq = 0; qq < 2; ++qq)                           \
        _Pragma("unroll") for (int n = 0; n < 4; ++n)                          \
            sacc[qq][n] = f32x4{0.f, 0.f, 0.f, 0.f};                           \
    const char* KB = (const char*)&Kl[BUF_][0];                                \
    __builtin_amdgcn_s_setprio(1);                                             \
    _Pragma("unroll") for (int kc = 0; kc < 4; ++kc) {                         \
      s16x8 kb[4];                                                             \
      _Pragma("unroll") for (int n = 0; n < 4; ++n)                            \
          kb[n] = *(const s16x8*)(KB + kaddr[kc] + n * 4096);                  \
      _Pragma("unroll") for (int qq = 0; qq < 2; ++qq)                         \
          _Pragma("unroll") for (int n = 0; n < 4; ++n)                        \
              sacc[qq][n] = __builtin_amdgcn_mfma_f32_16x16x32_bf16(           \
                  qf[qq][kc], kb[n], sacc[qq][n], 0, 0, 0);                    \
    }                                                                          \
    __builtin_amdgcn_s_setprio(0);                                             \
    /* V fragments -> registers once per tile (shared by both qq) */           \
    const char* VB = (const char*)&Vl[BUF_][0];                                \
    s16x8 vb[2][8];                                                            \
    _Pragma("unroll") for (int kc2 = 0; kc2 < 2; ++kc2)                        \
        _Pragma("unroll") for (int df = 0; df < 8; ++df)                       \
            vb[kc2][df] = *(const s16x8*)(VB + vaddr[kc2] + df * 2048);        \
    /* per-lane frag maxes; cross-lane reduce only on (rare) trigger */        \
    float mx4[2][4];                                                           \
    float need = 0.f;                                                          \
    _Pragma("unroll") for (int qq = 0; qq < 2; ++qq)                           \
        _Pragma("unroll") for (int r = 0; r < 4; ++r) {                        \
      mx4[qq][r] = fmaxf(fmaxf(sacc[qq][0][r], sacc[qq][1][r]),                \
                         fmaxf(sacc[qq][2][r], sacc[qq][3][r]));               \
      need = fmaxf(need, mx4[qq][r] - mrow[qq][r]);                            \
    }                                                                          \
    if (!__all(need <= 8.0f)) { /* T13: full reduce + rescale, rare */         \
      _Pragma("unroll") for (int qq = 0; qq < 2; ++qq)                         \
          _Pragma("unroll") for (int r = 0; r < 4; ++r) {                      \
        float mx = mx4[qq][r];                                                 \
        mx = fmaxf(mx, __shfl_xor(mx, 1));                                     \
        mx = fmaxf(mx, __shfl_xor(mx, 2));                                     \
        mx = fmaxf(mx, __shfl_xor(mx, 4));                                     \
        mx = fmaxf(mx, __shfl_xor(mx, 8));                                     \
        float mnew = fmaxf(mrow[qq][r], mx);                                   \
        float alpha = FAST_EXP2(mrow[qq][r] - mnew);                           \
        mrow[qq][r] = mnew;                                                    \
        lrow[qq][r] *= alpha;                                                  \
        _Pragma("unroll") for (int df = 0; df < 8; ++df)                       \
            oacc[qq][df][r] *= alpha;                                          \
      }                                                                        \
    }                                                                          \
    /* per-qq: exp2 -> P-write (reused 2KB region) -> PV from registers.  */  \
    /* qq1's VALU overlaps qq0's PV MFMAs; wave-private DS is in-order.   */  \
    _Pragma("unroll") for (int qq = 0; qq < 2; ++qq) {                         \
      _Pragma("unroll") for (int r = 0; r < 4; ++r) {                          \
        float rs = 0.f;                                                        \
        _Pragma("unroll") for (int n = 0; n < 4; ++n) {                        \
          float p = FAST_EXP2(sacc[qq][n][r] - mrow[qq][r]);                   \
          sacc[qq][n][r] = p;                                                  \
          rs += p;                                                             \
        }                                                                      \
        lrow[qq][r] += rs;                                                     \
      }                                                                        \
      _Pragma("unroll") for (int n = 0; n < 4; ++n)                            \
          _Pragma("unroll") for (int r = 0; r < 4; ++r) {                      \
        const int prow = g * 4 + r;                                            \
        const int psl = (n * 2 + (c16 >> 3)) ^ (prow & 7);                     \
        Pl[w][prow * 64 + (psl << 3) + (c16 & 7)] = bfc(sacc[qq][n][r]);       \
      }                                                                        \
      __builtin_amdgcn_s_setprio(1);                                           \
      _Pragma("unroll") for (int kc2 = 0; kc2 < 2; ++kc2) {                    \
        s16x8 pa = *(const s16x8*)(PW + vaddr[kc2]);                           \
        _Pragma("unroll") for (int df = 0; df < 8; ++df)                       \
            oacc[qq][df] = __builtin_amdgcn_mfma_f32_16x16x32_bf16(            \
                pa, vb[kc2][df], oacc[qq][df], 0, 0, 0);                       \
      }                                                                        \
      __builtin_amdgcn_s_setprio(0);                                           \
    }                                                                          \
  } while (0)

  STAGE(0, 0);
  __syncthreads();
  for (int t = 0; t < 2048; t += 128) {
    STAGE(t + 64, 1);     // prefetch next tile while computing current
    COMPUTE(0);
    __syncthreads();      // drains vmcnt -> buf1 ready, buf0 free
    if (t + 128 < 2048) STAGE(t + 128, 0);
    COMPUTE(1);
    __syncthreads();
  }
#undef STAGE
#undef COMPUTE

  // epilogue: reduce per-lane lrow partials, divide, write bf16 [B,S,D]
#pragma unroll
  for (int qq = 0; qq < 2; ++qq)
#pragma unroll
    for (int r = 0; r < 4; ++r) {
      float tot = lrow[qq][r];
      tot += __shfl_xor(tot, 1);
      tot += __shfl_xor(tot, 2);
      tot += __shfl_xor(tot, 4);
      tot += __shfl_xor(tot, 8);
      const float inv = 1.0f / tot;
      const int srow_ = q0 + qq * 16 + g * 4 + r;
#pragma unroll
      for (int df = 0; df < 8; ++df)
        Ob[(size_t)(b * 2048 + srow_) * 2048 + h * 128 + df * 16 + c16] =
            bfc(oacc[qq][df][r] * inv);
    }
}

// ---------------- launch ----------------
extern "C" void kernel_launch(void* const* d_in, const int* in_sizes, int n_in,
                              void* d_out, int out_size, void* d_ws, size_t ws_size,
                              hipStream_t stream) {
  const float* hs = (const float*)d_in[0];
  const float* Wq = (const float*)d_in[1];
  const float* Wk = (const float*)d_in[2];
  const float* Wv = (const float*)d_in[3];
  const float* Wo = (const float*)d_in[4];
  // d_in[5] medical_bias: per-head constant over softmax axis -> no-op.
  float* out = (float*)d_out;
  char* ws = (char*)d_ws;

  // workspace layout (bytes)
  unsigned short* hb   = (unsigned short*)(ws + 0);          // 16.78 MB (reused as Ob)
  unsigned short* wall = (unsigned short*)(ws + 16777216);   // 4 x 8.39 MB contiguous
  unsigned short* wqb  = wall;
  unsigned short* wkb  = wall + 4194304;
  unsigned short* wvb  = wall + 8388608;
  unsigned short* wob  = wall + 12582912;
  unsigned short* Qbb  = (unsigned short*)(ws + 50331648);   // 16.78 MB
  unsigned short* Kbb  = (unsigned short*)(ws + 67108864);   // 16.78 MB
  unsigned short* Vt   = (unsigned short*)(ws + 83886080);   // 16.78 MB
  float2*         tab2 = (float2*)(ws + 100663296);          // 1 MB
  unsigned short* Ob   = hb;  // hidden-bf16 region reused after QKV GEMM

  k_f2bf_all<<<2048, 256, 0, stream>>>(hs, Wq, Wk, Wv, Wo, hb, wall, tab2);

  k_gemm<<<dim3(16, 32, 3), 256, 0, stream>>>(hb, wqb, wkb, wvb, nullptr, Qbb,
                                              Kbb, Vt, tab2, 0);
  k_attn<<<dim3(16, 32), 256, 0, stream>>>(Qbb, Kbb, Vt, Ob);
  k_gemm<<<dim3(16, 32, 1), 256, 0, stream>>>(Ob, wob, nullptr, nullptr, out,
                                              nullptr, nullptr, nullptr, tab2, 1);
}

// Round 17
// 251.453 us; speedup vs baseline: 1.2269x; 1.2269x over previous
//
#include <hip/hip_runtime.h>
#include <hip/hip_bf16.h>
#include <stdint.h>

// HealthAttention: out = (softmax(rope(XWq^T) rope(XWk^T)^T / sqrt(128)) XWv^T) Wo^T
// B=2 S=2048 D=2048 H=16 DH=128.  medical_bias is per-head constant over the
// softmax axis -> softmax-invariant -> dropped.
// R17: byte-exact revert to R14 (session best, 251.7 us). Five structural
// rewrites (R12/R13/R15 QKV; R8/R16 attn) all regressed: QKV sits at the
// m97-structure ceiling (925 TF), attn is DS-pipe/chain balanced with all
// cheap levers applied, f2bf at HBM roofline. Further gains need asm-level
// schedule control (full 8-phase template / allocator steering).

#define B_ 2
#define S_ 2048
#define D_ 2048
#define H_ 16

typedef float f32x4 __attribute__((ext_vector_type(4)));
typedef short s16x8 __attribute__((ext_vector_type(8)));

__device__ __forceinline__ unsigned short f2bf(float f) {
  union { float f; uint32_t u; } c; c.f = f;
  return (unsigned short)((c.u + 0x7fffu + ((c.u >> 16) & 1u)) >> 16);
}

__device__ __forceinline__ unsigned short bfc(float f) {
  __hip_bfloat16 h = __float2bfloat16(f);
  unsigned short u;
  __builtin_memcpy(&u, &h, 2);
  return u;
}

#define FAST_EXP2(x) __builtin_amdgcn_exp2f(x)

__device__ __forceinline__ void gld_lds16(const void* g, void* l) {
  __builtin_amdgcn_global_load_lds(
      (const __attribute__((address_space(1))) uint32_t*)g,
      (__attribute__((address_space(3))) uint32_t*)l, 16, 0, 0);
}

// ------- fp32 -> bf16 convert (all 5 tensors) + rope table, one kernel -----
__global__ __launch_bounds__(256) void k_f2bf_all(
    const float* __restrict__ hs, const float* __restrict__ wq,
    const float* __restrict__ wk, const float* __restrict__ wv,
    const float* __restrict__ wo, unsigned short* __restrict__ hb,
    unsigned short* __restrict__ wall, float2* __restrict__ t2) {
  const int NH = 2097152, NW = 1048576;  // float4 units
  const int NF = NH + 4 * NW;            // convert work
  const int NT = 131072;                 // rope-table work (S*64)
  int i = blockIdx.x * 256 + threadIdx.x;
  const int stride = gridDim.x * 256;
  for (; i < NF + NT; i += stride) {
    if (i < NF) {
      f32x4 v;
      ushort4* dst;
      if (i < NH) {
        v = ((const f32x4*)hs)[i];
        dst = (ushort4*)hb + i;
      } else {
        const int j = i - NH;
        const int rgn = j >> 20;
        const int o = j & (NW - 1);
        const float* s = (rgn == 0) ? wq : (rgn == 1) ? wk : (rgn == 2) ? wv : wo;
        v = ((const f32x4*)s)[o];
        dst = (ushort4*)wall + j;
      }
      ushort4 u;
      u.x = f2bf(v.x); u.y = f2bf(v.y); u.z = f2bf(v.z); u.w = f2bf(v.w);
      *dst = u;
    } else {
      const int t = i - NF;              // 0..131071
      const int s = t >> 6, j = t & 63;
      float inv = expf(-(float)j * (1.0f / 64.0f) * 9.210340371976184f);
      float sv, cv;
      sincosf((float)s * inv, &sv, &cv);
      t2[t] = float2{cv, sv};
    }
  }
}

// ---------------- GEMM: C[M,N] = A[M,K] @ W[N,K]^T  (bf16 in, fp32 acc) -----
// 128x128 tile, BK=64, 4 row-stacked waves (each: 32 rows x 128 cols),
// 16x16x32 MFMA, XCD-swizzled grid, double-buffered swizzled LDS,
// early-STAGE pipeline (1 barrier per K-step).
// plain=1: fp32 to C0.  plain=0: z=0 -> RoPE+scale -> bf16 Qo;
// z=1 -> RoPE -> bf16 Ko; z=2 -> bf16 transposed per-head to VT.
__global__ __launch_bounds__(256, 2) void k_gemm(
    const unsigned short* __restrict__ A,
    const unsigned short* __restrict__ W0,
    const unsigned short* __restrict__ W1,
    const unsigned short* __restrict__ W2,
    float* __restrict__ C0,
    unsigned short* __restrict__ Qo,
    unsigned short* __restrict__ Ko,
    unsigned short* __restrict__ VT,
    const float2* __restrict__ tab,
    int plain) {
  __shared__ unsigned short Al[2][128 * 64];
  __shared__ unsigned short Bl[2][128 * 64];

  // bijective XCD remap: hw linear id (x fastest, z slowest), nwg % 8 == 0
  const int l0 = ((int)blockIdx.z * 32 + (int)blockIdx.y) * 16 + (int)blockIdx.x;
  const int qx = ((int)gridDim.z * 512) >> 3;  // blocks per XCD
  const int wg = (l0 & 7) * qx + (l0 >> 3);
  const int z = wg >> 9;
  const unsigned short* __restrict__ Wp = (z == 0) ? W0 : (z == 1) ? W1 : W2;

  const int tid = threadIdx.x;
  const int w = tid >> 6;
  const int l = tid & 63;
  const int row0 = ((wg >> 4) & 31) * 128;
  const int col0 = (wg & 15) * 128;

  const int c16 = l & 15, g = l >> 4;
  const int cx = c16 & 7;

  // staging: lane covers row jj*8 + (l>>3), 16B slot (l&7); source slot
  // pre-swizzled so LDS[row][slot] = global[row][slot ^ (row&7)].
  const int srow = l >> 3;
  const int scol = ((l & 7) ^ (l >> 3)) << 3;  // source col in bf16 elems

  // ds_read lane bases (bytes): addr = base + kbase[kk] (+ m*2048 / n*2048)
  int kbase[2];
#pragma unroll
  for (int kk = 0; kk < 2; ++kk)
    kbase[kk] = c16 * 128 + (((kk * 4 + g) ^ cx) << 4);
  const char* AW0 = (const char*)&Al[0][0] + w * 4096;
  const char* AW1 = (const char*)&Al[1][0] + w * 4096;
  const char* BB0 = (const char*)&Bl[0][0];
  const char* BB1 = (const char*)&Bl[1][0];

  f32x4 acc[2][8];
#pragma unroll
  for (int m = 0; m < 2; ++m)
#pragma unroll
    for (int n = 0; n < 8; ++n)
      acc[m][n] = f32x4{0.f, 0.f, 0.f, 0.f};

#define STAGE_G(K0, BUF)                                                       \
  do {                                                                         \
    _Pragma("unroll") for (int i = 0; i < 4; ++i) {                            \
      const int jj = (w << 2) + i;                                             \
      gld_lds16(&A[(size_t)(row0 + (jj << 3) + srow) * 2048 + (K0) + scol],    \
                &Al[BUF][jj * 512]);                                           \
      gld_lds16(&Wp[(size_t)(col0 + (jj << 3) + srow) * 2048 + (K0) + scol],   \
                &Bl[BUF][jj * 512]);                                           \
    }                                                                          \
  } while (0)

#define COMPUTE_G(AW, BBp)                                                     \
  do {                                                                         \
    _Pragma("unroll") for (int kk = 0; kk < 2; ++kk) {                         \
      s16x8 a[2], b[8];                                                        \
      _Pragma("unroll") for (int m = 0; m < 2; ++m)                            \
          a[m] = *(const s16x8*)((AW) + m * 2048 + kbase[kk]);                 \
      _Pragma("unroll") for (int n = 0; n < 8; ++n)                            \
          b[n] = *(const s16x8*)((BBp) + n * 2048 + kbase[kk]);                \
      __builtin_amdgcn_s_setprio(1);                                           \
      _Pragma("unroll") for (int m = 0; m < 2; ++m)                            \
          _Pragma("unroll") for (int n = 0; n < 8; ++n)                        \
              acc[m][n] = __builtin_amdgcn_mfma_f32_16x16x32_bf16(             \
                  a[m], b[n], acc[m][n], 0, 0, 0);                             \
      __builtin_amdgcn_s_setprio(0);                                           \
    }                                                                          \
  } while (0)

  STAGE_G(0, 0);
  __syncthreads();
  for (int k0 = 0; k0 < 2048; k0 += 128) {
    STAGE_G(k0 + 64, 1);  // prefetch next K-tile while computing current
    COMPUTE_G(AW0, BB0);
    __syncthreads();      // vmcnt drain amortized under the 32 MFMAs above
    if (k0 + 128 < 2048) STAGE_G(k0 + 128, 0);
    COMPUTE_G(AW1, BB1);
    __syncthreads();
  }
#undef STAGE_G
#undef COMPUTE_G

  if (plain) {
#pragma unroll
    for (int m = 0; m < 2; ++m) {
      const int gr = row0 + w * 32 + m * 16 + g * 4;
#pragma unroll
      for (int n = 0; n < 8; ++n) {
        const int gc = col0 + n * 16 + c16;
#pragma unroll
        for (int r = 0; r < 4; ++r)
          C0[(size_t)(gr + r) * 2048 + gc] = acc[m][n][r];
      }
    }
  } else if (z == 2) {
    // V: write bf16 transposed per-head: VT[((b*16+h)*128+dh)*2048 + s]
#pragma unroll
    for (int m = 0; m < 2; ++m) {
      const int gr = row0 + w * 32 + m * 16 + g * 4;  // 4 consecutive s
      const int b_ = gr >> 11, s_ = gr & 2047;
#pragma unroll
      for (int n = 0; n < 8; ++n) {
        const int gc = col0 + n * 16 + c16;  // h*128+dh
        ushort4 o;
        o.x = f2bf(acc[m][n][0]);
        o.y = f2bf(acc[m][n][1]);
        o.z = f2bf(acc[m][n][2]);
        o.w = f2bf(acc[m][n][3]);
        *(ushort4*)&VT[((size_t)(b_ * 2048 + gc)) * 2048 + s_] = o;
      }
    }
  } else {
    // Q/K: in-register RoPE.  cols col0 + j and col0 + 64 + j are lane-local
    // (acc[m][n], acc[m][n+4]).  Q additionally scaled by (1/sqrt(128))*log2e
    // so attention can use exp2.
    unsigned short* __restrict__ O = z ? Ko : Qo;
    const float sc = z ? 1.0f : (0.08838834764831845f * 1.4426950408889634f);
#pragma unroll
    for (int m = 0; m < 2; ++m) {
#pragma unroll
      for (int r = 0; r < 4; ++r) {
        const int gr = row0 + w * 32 + m * 16 + g * 4 + r;
        const int s_ = gr & 2047;
#pragma unroll
        for (int n = 0; n < 4; ++n) {
          const float2 f = tab[s_ * 64 + n * 16 + c16];
          const float x1 = acc[m][n][r], x2 = acc[m][n + 4][r];
          O[(size_t)gr * 2048 + col0 + n * 16 + c16] =
              f2bf((x1 * f.x - x2 * f.y) * sc);
          O[(size_t)gr * 2048 + col0 + 64 + n * 16 + c16] =
              f2bf((x2 * f.x + x1 * f.y) * sc);
        }
      }
    }
  }
}

// ---------------- flash attention (pipelined, swizzled LDS) ----------------
// grid (16, 32): 512 blocks, XCD-remapped so each (b,h) lives on one XCD.
// 4 waves x 32 q-rows; K/V double-buffered; 1 barrier per 64-key tile.
// Per-qq P buffer (2KB/wave, reused qq0->qq1); PV(qq0) overlaps softmax(qq1).
// Scores arrive pre-scaled by (1/sqrt(128))*log2e -> exp2 softmax.
__global__ __launch_bounds__(256, 2) void k_attn(
    const unsigned short* __restrict__ Qb,
    const unsigned short* __restrict__ Kb,
    const unsigned short* __restrict__ Vt,
    unsigned short* __restrict__ Ob) {
  __shared__ unsigned short Kl[2][64 * 128];   // [key][d]  swizzled, 2x16KB
  __shared__ unsigned short Vl[2][128 * 64];   // [d][key]  swizzled, 2x16KB
  __shared__ unsigned short Pl[4][16 * 64];    // per-wave per-qq P, 8KB

  const int l0 = (int)blockIdx.y * 16 + (int)blockIdx.x;
  const int wg = (l0 & 7) * 64 + (l0 >> 3);
  const int bh = wg >> 4;
  const int b = bh >> 4, h = bh & 15;

  const int tid = threadIdx.x, w = tid >> 6, l = tid & 63;
  const int q0 = (wg & 15) * 128 + w * 32;
  const int g = l >> 4, c16 = l & 15;
  const int cx = c16 & 7;  // row&7 for rows of form n*16+c16

  // hoisted swizzled LDS read offsets (bytes, lane-only)
  int kaddr[4], vaddr[2];
#pragma unroll
  for (int kc = 0; kc < 4; ++kc)
    kaddr[kc] = c16 * 256 + ((((kc * 4 + g) ^ cx)) << 4);
#pragma unroll
  for (int kc2 = 0; kc2 < 2; ++kc2)
    vaddr[kc2] = c16 * 128 + ((((kc2 * 4 + g) ^ cx)) << 4);
  const char* PW = (const char*)&Pl[w][0];

  // Q fragments in registers (pre-scaled by (1/sqrt(128))*log2e)
  s16x8 qf[2][4];
#pragma unroll
  for (int qq = 0; qq < 2; ++qq)
#pragma unroll
    for (int kc = 0; kc < 4; ++kc)
      qf[qq][kc] = *(const s16x8*)&Qb[(size_t)(b * 2048 + q0 + qq * 16 + c16) * 2048 +
                                      h * 128 + kc * 32 + g * 8];

  f32x4 oacc[2][8];
  float mrow[2][4], lrow[2][4];  // lrow: per-lane partial sums
#pragma unroll
  for (int qq = 0; qq < 2; ++qq) {
#pragma unroll
    for (int df = 0; df < 8; ++df) oacc[qq][df] = f32x4{0.f, 0.f, 0.f, 0.f};
#pragma unroll
    for (int r = 0; r < 4; ++r) { mrow[qq][r] = -INFINITY; lrow[qq][r] = 0.f; }
  }

#define STAGE(T, BUF)                                                          \
  do {                                                                         \
    _Pragma("unroll") for (int i = 0; i < 4; ++i) {                            \
      const int jj = (w << 2) + i;                                             \
      const int krow = jj * 4 + (l >> 4);                                      \
      const int kslot = (l & 15) ^ (krow & 7);                                 \
      gld_lds16(&Kb[(size_t)(b * 2048 + (T) + krow) * 2048 + h * 128 +        \
                    (kslot << 3)],                                             \
                &Kl[BUF][jj * 512]);                                           \
      const int vrow = jj * 8 + (l >> 3);                                      \
      const int vslot = (l & 7) ^ (vrow & 7);                                  \
      gld_lds16(&Vt[(size_t)(bh * 128 + vrow) * 2048 + (T) + (vslot << 3)],    \
                &Vl[BUF][jj * 512]);                                           \
    }                                                                          \
  } while (0)

#define COMPUTE(BUF_)                                                          \
  do {                                                                         \
    f32x4 sacc[2][4];                                                          \
    _Pragma("unroll") for (int qq = 0; qq < 2; ++qq)                           \
        _Pragma("unroll") for (int n = 0; n < 4; ++n)                          \
            sacc[qq][n] = f32x4{0.f, 0.f, 0.f, 0.f};                           \
    const char* KB = (const char*)&Kl[BUF_][0];                                \
    __builtin_amdgcn_s_setprio(1);                                             \
    _Pragma("unroll") for (int kc = 0; kc < 4; ++kc) {                         \
      s16x8 kb[4];                                                             \
      _Pragma("unroll") for (int n = 0; n < 4; ++n)                            \
          kb[n] = *(const s16x8*)(KB + kaddr[kc] + n * 4096);                  \
      _Pragma("unroll") for (int qq = 0; qq < 2; ++qq)                         \
          _Pragma("unroll") for (int n = 0; n < 4; ++n)                        \
              sacc[qq][n] = __builtin_amdgcn_mfma_f32_16x16x32_bf16(           \
                  qf[qq][kc], kb[n], sacc[qq][n], 0, 0, 0);                    \
    }                                                                          \
    __builtin_amdgcn_s_setprio(0);                                             \
    /* per-lane frag maxes; cross-lane reduce only on (rare) trigger */        \
    float mx4[2][4];                                                           \
    float need = 0.f;                                                          \
    _Pragma("unroll") for (int qq = 0; qq < 2; ++qq)                           \
        _Pragma("unroll") for (int r = 0; r < 4; ++r) {                        \
      mx4[qq][r] = fmaxf(fmaxf(sacc[qq][0][r], sacc[qq][1][r]),                \
                         fmaxf(sacc[qq][2][r], sacc[qq][3][r]));               \
      need = fmaxf(need, mx4[qq][r] - mrow[qq][r]);                            \
    }                                                                          \
    if (!__all(need <= 8.0f)) { /* T13: full reduce + rescale, rare */         \
      _Pragma("unroll") for (int qq = 0; qq < 2; ++qq)                         \
          _Pragma("unroll") for (int r = 0; r < 4; ++r) {                      \
        float mx = mx4[qq][r];                                                 \
        mx = fmaxf(mx, __shfl_xor(mx, 1));                                     \
        mx = fmaxf(mx, __shfl_xor(mx, 2));                                     \
        mx = fmaxf(mx, __shfl_xor(mx, 4));                                     \
        mx = fmaxf(mx, __shfl_xor(mx, 8));                                     \
        float mnew = fmaxf(mrow[qq][r], mx);                                   \
        float alpha = FAST_EXP2(mrow[qq][r] - mnew);                           \
        mrow[qq][r] = mnew;                                                    \
        lrow[qq][r] *= alpha;                                                  \
        _Pragma("unroll") for (int df = 0; df < 8; ++df)                       \
            oacc[qq][df][r] *= alpha;                                          \
      }                                                                        \
    }                                                                          \
    const char* VB = (const char*)&Vl[BUF_][0];                                \
    /* per-qq: exp2 -> P-write (reused 2KB region) -> PV.  qq1's VALU     */   \
    /* overlaps qq0's PV MFMAs; wave-private region, DS in-order per wave. */  \
    _Pragma("unroll") for (int qq = 0; qq < 2; ++qq) {                         \
      _Pragma("unroll") for (int r = 0; r < 4; ++r) {                          \
        float rs = 0.f;                                                        \
        _Pragma("unroll") for (int n = 0; n < 4; ++n) {                        \
          float p = FAST_EXP2(sacc[qq][n][r] - mrow[qq][r]);                   \
          sacc[qq][n][r] = p;                                                  \
          rs += p;                                                             \
        }                                                                      \
        lrow[qq][r] += rs;                                                     \
      }                                                                        \
      _Pragma("unroll") for (int n = 0; n < 4; ++n)                            \
          _Pragma("unroll") for (int r = 0; r < 4; ++r) {                      \
        const int prow = g * 4 + r;                                            \
        const int psl = (n * 2 + (c16 >> 3)) ^ (prow & 7);                     \
        Pl[w][prow * 64 + (psl << 3) + (c16 & 7)] = bfc(sacc[qq][n][r]);       \
      }                                                                        \
      __builtin_amdgcn_s_setprio(1);                                           \
      _Pragma("unroll") for (int kc2 = 0; kc2 < 2; ++kc2) {                    \
        s16x8 pa = *(const s16x8*)(PW + vaddr[kc2]);                           \
        _Pragma("unroll") for (int df = 0; df < 8; ++df) {                     \
          s16x8 vb = *(const s16x8*)(VB + vaddr[kc2] + df * 2048);             \
          oacc[qq][df] = __builtin_amdgcn_mfma_f32_16x16x32_bf16(              \
              pa, vb, oacc[qq][df], 0, 0, 0);                                  \
        }                                                                      \
      }                                                                        \
      __builtin_amdgcn_s_setprio(0);                                           \
    }                                                                          \
  } while (0)

  STAGE(0, 0);
  __syncthreads();
  for (int t = 0; t < 2048; t += 128) {
    STAGE(t + 64, 1);     // prefetch next tile while computing current
    COMPUTE(0);
    __syncthreads();      // drains vmcnt -> buf1 ready, buf0 free
    if (t + 128 < 2048) STAGE(t + 128, 0);
    COMPUTE(1);
    __syncthreads();
  }
#undef STAGE
#undef COMPUTE

  // epilogue: reduce per-lane lrow partials, divide, write bf16 [B,S,D]
#pragma unroll
  for (int qq = 0; qq < 2; ++qq)
#pragma unroll
    for (int r = 0; r < 4; ++r) {
      float tot = lrow[qq][r];
      tot += __shfl_xor(tot, 1);
      tot += __shfl_xor(tot, 2);
      tot += __shfl_xor(tot, 4);
      tot += __shfl_xor(tot, 8);
      const float inv = 1.0f / tot;
      const int srow_ = q0 + qq * 16 + g * 4 + r;
#pragma unroll
      for (int df = 0; df < 8; ++df)
        Ob[(size_t)(b * 2048 + srow_) * 2048 + h * 128 + df * 16 + c16] =
            bfc(oacc[qq][df][r] * inv);
    }
}

// ---------------- launch ----------------
extern "C" void kernel_launch(void* const* d_in, const int* in_sizes, int n_in,
                              void* d_out, int out_size, void* d_ws, size_t ws_size,
                              hipStream_t stream) {
  const float* hs = (const float*)d_in[0];
  const float* Wq = (const float*)d_in[1];
  const float* Wk = (const float*)d_in[2];
  const float* Wv = (const float*)d_in[3];
  const float* Wo = (const float*)d_in[4];
  // d_in[5] medical_bias: per-head constant over softmax axis -> no-op.
  float* out = (float*)d_out;
  char* ws = (char*)d_ws;

  // workspace layout (bytes)
  unsigned short* hb   = (unsigned short*)(ws + 0);          // 16.78 MB (reused as Ob)
  unsigned short* wall = (unsigned short*)(ws + 16777216);   // 4 x 8.39 MB contiguous
  unsigned short* wqb  = wall;
  unsigned short* wkb  = wall + 4194304;
  unsigned short* wvb  = wall + 8388608;
  unsigned short* wob  = wall + 12582912;
  unsigned short* Qbb  = (unsigned short*)(ws + 50331648);   // 16.78 MB
  unsigned short* Kbb  = (unsigned short*)(ws + 67108864);   // 16.78 MB
  unsigned short* Vt   = (unsigned short*)(ws + 83886080);   // 16.78 MB
  float2*         tab2 = (float2*)(ws + 100663296);          // 1 MB
  unsigned short* Ob   = hb;  // hidden-bf16 region reused after QKV GEMM

  k_f2bf_all<<<2048, 256, 0, stream>>>(hs, Wq, Wk, Wv, Wo, hb, wall, tab2);

  k_gemm<<<dim3(16, 32, 3), 256, 0, stream>>>(hb, wqb, wkb, wvb, nullptr, Qbb,
                                              Kbb, Vt, tab2, 0);
  k_attn<<<dim3(16, 32), 256, 0, stream>>>(Qbb, Kbb, Vt, Ob);
  k_gemm<<<dim3(16, 32, 1), 256, 0, stream>>>(Ob, wob, nullptr, nullptr, out,
                                              nullptr, nullptr, nullptr, tab2, 1);
}